// Round 1
// baseline (703.661 us; speedup 1.0000x reference)
//
#include <hip/hip_runtime.h>
#include <hip/hip_bf16.h>
#include <cstdint>
#include <cstddef>

// ---------------------------------------------------------------------------
// VectorMerge: two-stream LN -> leaky_relu -> dual Dense (out + gate),
// output = sigmoid(gate_pre) * (out1 + out2).
// Strategy: concat streams along K (f=[f1|f2], K=1536), concat the two weight
// matrices along N conceptually -> one dual-accumulator bf16 MFMA GEMM.
// ---------------------------------------------------------------------------

#define LN_EPS 1e-6f
#define NEG_SLOPE 0.01f

#define B_ROWS 32768
#define D1 1024
#define D2 512
#define KTOT 1536      // D1 + D2
#define NOUT 1024

#define BM 128
#define BN 128
#define BK 64
#define NT_N (NOUT / BN)          // 8
#define NT_M (B_ROWS / BM)        // 256
#define NBLK (NT_M * NT_N)        // 2048

typedef __attribute__((ext_vector_type(8))) short bf16x8;
typedef __attribute__((ext_vector_type(4))) float f32x4;

__device__ __forceinline__ unsigned short f2bf(float x) {
  __hip_bfloat16 h = __float2bfloat16(x);
  return *reinterpret_cast<unsigned short*>(&h);
}

__device__ __forceinline__ void gload_lds16(const void* g, void* l) {
  __builtin_amdgcn_global_load_lds(
      (const __attribute__((address_space(1))) unsigned int*)g,
      (__attribute__((address_space(3))) unsigned int*)l, 16, 0, 0);
}

// ---------------------------------------------------------------------------
// Kernel 0: build Wt[2048][1536] bf16 in ws.
//   Wt[n2][k]: n2<1024 -> out-weights column n2; n2>=1024 -> gate column n2-1024
//   k<1024 from stream-1 matrices [1024,1024]; k>=1024 from stream-2 [512,1024]
// LDS-tiled 32x32 transpose so both read and write are coalesced.
// ---------------------------------------------------------------------------
__global__ __launch_bounds__(256)
void prep_wt(const float* __restrict__ Wo1, const float* __restrict__ Wo2,
             const float* __restrict__ Wg1, const float* __restrict__ Wg2,
             unsigned short* __restrict__ Wt) {
  __shared__ float tile[32][33];
  const int k0 = blockIdx.x * 32;   // 48 tiles over K=1536
  const int n20 = blockIdx.y * 32;  // 64 tiles over N2=2048
  const int tx = threadIdx.x;       // 0..31
  const int ty = threadIdx.y;       // 0..7
  const bool gate = (n20 >= 1024);
  const int n = (n20 & 1023) + tx;
#pragma unroll
  for (int r = 0; r < 4; ++r) {
    int k = k0 + ty + r * 8;
    float v;
    if (k < D1) v = (gate ? Wg1 : Wo1)[(size_t)k * NOUT + n];
    else        v = (gate ? Wg2 : Wo2)[(size_t)(k - D1) * NOUT + n];
    tile[ty + r * 8][tx] = v;
  }
  __syncthreads();
#pragma unroll
  for (int r = 0; r < 4; ++r) {
    int n2 = n20 + ty + r * 8;
    Wt[(size_t)n2 * KTOT + k0 + tx] = f2bf(tile[tx][ty + r * 8]);
  }
}

// ---------------------------------------------------------------------------
// Kernel 1: LayerNorm + leaky_relu, fp32 in -> bf16 out (packed VEC-wide).
// One 256-thread block per row. f row stride = 1536 (concat layout).
// ---------------------------------------------------------------------------
template <int D, int VEC>
__global__ __launch_bounds__(256)
void ln_leaky(const float* __restrict__ x, const float* __restrict__ sc,
              const float* __restrict__ bi, unsigned short* __restrict__ f,
              int col_off) {
  static_assert(D == 256 * VEC, "block covers the row exactly");
  const int row = blockIdx.x;
  const int t = threadIdx.x;
  const float* xr = x + (size_t)row * D;

  float v[VEC];
  if constexpr (VEC == 4) {
    float4 lv = reinterpret_cast<const float4*>(xr)[t];
    v[0] = lv.x; v[1] = lv.y; v[2] = lv.z; v[3] = lv.w;
  } else {
    float2 lv = reinterpret_cast<const float2*>(xr)[t];
    v[0] = lv.x; v[1] = lv.y;
  }

  float s = 0.f, ss = 0.f;
#pragma unroll
  for (int i = 0; i < VEC; ++i) { s += v[i]; ss += v[i] * v[i]; }

  // wave butterfly reduce (64 lanes), then cross-wave via LDS
#pragma unroll
  for (int o = 32; o > 0; o >>= 1) {
    s += __shfl_xor(s, o);
    ss += __shfl_xor(ss, o);
  }
  __shared__ float red[2][4];
  if ((t & 63) == 0) { red[0][t >> 6] = s; red[1][t >> 6] = ss; }
  __syncthreads();
  s = red[0][0] + red[0][1] + red[0][2] + red[0][3];
  ss = red[1][0] + red[1][1] + red[1][2] + red[1][3];

  const float mean = s / (float)D;
  const float var = ss / (float)D - mean * mean;
  const float rstd = rsqrtf(var + LN_EPS);

  unsigned short o16[VEC];
#pragma unroll
  for (int i = 0; i < VEC; ++i) {
    int c = t * VEC + i;
    float y = (v[i] - mean) * rstd * sc[c] + bi[c];
    y = (y > 0.f) ? y : NEG_SLOPE * y;
    o16[i] = f2bf(y);
  }
  unsigned short* dst = f + (size_t)row * KTOT + col_off + t * VEC;
  if constexpr (VEC == 4) {
    ushort4 pk; pk.x = o16[0]; pk.y = o16[1]; pk.z = o16[2]; pk.w = o16[3];
    *reinterpret_cast<ushort4*>(dst) = pk;
  } else {
    ushort2 pk; pk.x = o16[0]; pk.y = o16[1];
    *reinterpret_cast<ushort2*>(dst) = pk;
  }
}

// ---------------------------------------------------------------------------
// Kernel 2: dual-accumulator bf16 MFMA GEMM + gated epilogue.
//   C_out = f @ Wt[0:1024]^T,  C_gate = f @ Wt[1024:2048]^T
//   Out = sigmoid(C_gate + bg1+bg2) * (C_out + bo1+bo2)
// 128x128 tile, BK=64, 4 waves (each owns a 64x64 quadrant, 4x4 16x16 frags).
// global_load_lds(16B) staging, XOR-swizzled LDS (swizzle applied on the
// GLOBAL source address, since global_load_lds writes linearly).
// ---------------------------------------------------------------------------
__global__ __launch_bounds__(256)
void fused_dual_gemm(const unsigned short* __restrict__ F,   // [32768][1536] bf16
                     const unsigned short* __restrict__ Wt,  // [2048][1536] bf16
                     const float* __restrict__ bo1, const float* __restrict__ bo2,
                     const float* __restrict__ bg1, const float* __restrict__ bg2,
                     float* __restrict__ Out) {
  __shared__ __align__(16) unsigned short sA[BM * BK];
  __shared__ __align__(16) unsigned short sBo[BN * BK];
  __shared__ __align__(16) unsigned short sBg[BN * BK];

  // XCD-aware bijective swizzle: 2048 % 8 == 0
  const int bid = blockIdx.x;
  const int swz = (bid & 7) * (NBLK / 8) + (bid >> 3);
  const int tm = swz / NT_N;
  const int tn = swz % NT_N;
  const int m0 = tm * BM;
  const int n0 = tn * BN;

  const int t = threadIdx.x;
  const int lane = t & 63;
  const int wave = t >> 6;
  const int wr = wave >> 1;  // wave row 0..1  (64-row stripes)
  const int wc = wave & 1;   // wave col 0..1  (64-col stripes)

  f32x4 acc_o[4][4], acc_g[4][4];
#pragma unroll
  for (int i = 0; i < 4; ++i)
#pragma unroll
    for (int j = 0; j < 4; ++j) {
      acc_o[i][j] = (f32x4)0.f;
      acc_g[i][j] = (f32x4)0.f;
    }

  for (int kt = 0; kt < KTOT / BK; ++kt) {
    const int k0 = kt * BK;
    // ---- stage A, Bo, Bg tiles (each 128x64 bf16 = 16KB = 4 issues x 256thr x 16B)
    // LDS is linear: byte P holds logical (row = P/128, kbyte = (P%128) ^ ((row&7)<<4)).
    // So the global source k-offset is pre-swizzled: koff = 8*((t&7)^(row&7)).
#pragma unroll
    for (int is = 0; is < 4; ++is) {
      const int row = is * 32 + (t >> 3);
      const int koff = 8 * ((t & 7) ^ (row & 7));
      const size_t e = (size_t)(is * 256 + t) * 8;  // element offset in LDS tile
      gload_lds16(F + (size_t)(m0 + row) * KTOT + k0 + koff, &sA[e]);
      gload_lds16(Wt + (size_t)(n0 + row) * KTOT + k0 + koff, &sBo[e]);
      gload_lds16(Wt + (size_t)(1024 + n0 + row) * KTOT + k0 + koff, &sBg[e]);
    }
    __syncthreads();  // compiler emits s_waitcnt vmcnt(0) before barrier

    // ---- compute: 2 kk-steps of K=32, 4x4 frags, dual accumulators
#pragma unroll
    for (int kk = 0; kk < 2; ++kk) {
      bf16x8 af[4], bof[4], bgf[4];
      const int kb = kk * 64 + (lane >> 4) * 16;  // byte offset of this lane's 8 k-elems
#pragma unroll
      for (int i = 0; i < 4; ++i) {
        const int ar = wr * 64 + i * 16 + (lane & 15);
        af[i] = *(const bf16x8*)((const char*)sA + ar * 128 + (kb ^ ((ar & 7) << 4)));
        const int br = wc * 64 + i * 16 + (lane & 15);
        const int baddr = br * 128 + (kb ^ ((br & 7) << 4));
        bof[i] = *(const bf16x8*)((const char*)sBo + baddr);
        bgf[i] = *(const bf16x8*)((const char*)sBg + baddr);
      }
#pragma unroll
      for (int i = 0; i < 4; ++i)
#pragma unroll
        for (int j = 0; j < 4; ++j) {
          acc_o[i][j] = __builtin_amdgcn_mfma_f32_16x16x32_bf16(af[i], bof[j], acc_o[i][j], 0, 0, 0);
          acc_g[i][j] = __builtin_amdgcn_mfma_f32_16x16x32_bf16(af[i], bgf[j], acc_g[i][j], 0, 0, 0);
        }
    }
    __syncthreads();  // before next stage overwrites LDS
  }

  // ---- epilogue: D[row=(lane>>4)*4+r][col=lane&15] per 16x16 frag
#pragma unroll
  for (int j = 0; j < 4; ++j) {
    const int n = n0 + wc * 64 + j * 16 + (lane & 15);
    const float bo = bo1[n] + bo2[n];
    const float bg = bg1[n] + bg2[n];
#pragma unroll
    for (int i = 0; i < 4; ++i) {
      const int mbase = m0 + wr * 64 + i * 16 + (lane >> 4) * 4;
#pragma unroll
      for (int r = 0; r < 4; ++r) {
        const float o = acc_o[i][j][r] + bo;
        const float g = acc_g[i][j][r] + bg;
        const float sgm = 1.f / (1.f + __expf(-g));
        Out[(size_t)(mbase + r) * NOUT + n] = sgm * o;
      }
    }
  }
}

// ---------------------------------------------------------------------------
extern "C" void kernel_launch(void* const* d_in, const int* in_sizes, int n_in,
                              void* d_out, int out_size, void* d_ws, size_t ws_size,
                              hipStream_t stream) {
  const float* x1 = (const float*)d_in[0];
  const float* x2 = (const float*)d_in[1];
  const float* ln_s1 = (const float*)d_in[2];
  const float* ln_b1 = (const float*)d_in[3];
  const float* ln_s2 = (const float*)d_in[4];
  const float* ln_b2 = (const float*)d_in[5];
  const float* Wo1 = (const float*)d_in[6];
  const float* bo1 = (const float*)d_in[7];
  const float* Wo2 = (const float*)d_in[8];
  const float* bo2 = (const float*)d_in[9];
  const float* Wg1 = (const float*)d_in[10];
  const float* bg1 = (const float*)d_in[11];
  const float* Wg2 = (const float*)d_in[12];
  const float* bg2 = (const float*)d_in[13];
  float* out = (float*)d_out;

  // workspace layout: f bf16 [32768][1536] then Wt bf16 [2048][1536]
  unsigned short* f = (unsigned short*)d_ws;
  const size_t F_BYTES = (size_t)B_ROWS * KTOT * 2;  // 96 MiB
  unsigned short* Wt = (unsigned short*)((char*)d_ws + F_BYTES);

  // 0) weight transpose+convert (independent)
  prep_wt<<<dim3(KTOT / 32, 2048 / 32), dim3(32, 8), 0, stream>>>(Wo1, Wo2, Wg1, Wg2, Wt);
  // 1) LN + leaky per stream -> f (concat along K)
  ln_leaky<D1, 4><<<B_ROWS, 256, 0, stream>>>(x1, ln_s1, ln_b1, f, 0);
  ln_leaky<D2, 2><<<B_ROWS, 256, 0, stream>>>(x2, ln_s2, ln_b2, f, D1);
  // 2) fused dual GEMM + gated epilogue
  fused_dual_gemm<<<NBLK, 256, 0, stream>>>(f, Wt, bo1, bo2, bg1, bg2, out);
}

// Round 2
// 519.223 us; speedup vs baseline: 1.3552x; 1.3552x over previous
//
#include <hip/hip_runtime.h>
#include <hip/hip_bf16.h>
#include <cstdint>
#include <cstddef>

// ---------------------------------------------------------------------------
// VectorMerge: two-stream LN -> leaky_relu -> dual Dense (out + gate),
// output = sigmoid(gate_pre) * (out1 + out2).
// f = [f1|f2] (K=1536), Wt = [Wout; Wgate] (2048 x 1536, k-contiguous bf16).
// GEMM: 256x128 dual-accumulator tile (acts like 256x256 for LDS efficiency),
// BK=32, 8 waves, triple-buffered LDS, 2-deep prefetch, counted vmcnt.
// ---------------------------------------------------------------------------

#define LN_EPS 1e-6f
#define NEG_SLOPE 0.01f

#define B_ROWS 32768
#define D1 1024
#define D2 512
#define KTOT 1536
#define NOUT 1024

#define BM 256
#define BN 128
#define BK 32
#define THREADS 512
#define KSTEPS (KTOT / BK)          // 48
#define NT_M (B_ROWS / BM)          // 128
#define NT_N (NOUT / BN)            // 8
#define NBLK (NT_M * NT_N)          // 1024

#define A_BYTES (BM * BK * 2)       // 16384
#define B_BYTES (BN * BK * 2)       // 8192
#define BUF_BYTES (A_BYTES + 2 * B_BYTES)  // 32768
#define OFF_BO A_BYTES
#define OFF_BG (A_BYTES + B_BYTES)

typedef __attribute__((ext_vector_type(8))) short bf16x8;
typedef __attribute__((ext_vector_type(4))) float f32x4;

__device__ __forceinline__ unsigned short f2bf(float x) {
  __hip_bfloat16 h = __float2bfloat16(x);
  return *reinterpret_cast<unsigned short*>(&h);
}

__device__ __forceinline__ void gload_lds16(const void* g, void* l) {
  __builtin_amdgcn_global_load_lds(
      (const __attribute__((address_space(1))) unsigned int*)g,
      (__attribute__((address_space(3))) unsigned int*)l, 16, 0, 0);
}

// ---------------------------------------------------------------------------
// Kernel 0: build Wt[2048][1536] bf16 (n-major, k-contiguous) in ws.
// ---------------------------------------------------------------------------
__global__ __launch_bounds__(256)
void prep_wt(const float* __restrict__ Wo1, const float* __restrict__ Wo2,
             const float* __restrict__ Wg1, const float* __restrict__ Wg2,
             unsigned short* __restrict__ Wt) {
  __shared__ float tile[32][33];
  const int k0 = blockIdx.x * 32;
  const int n20 = blockIdx.y * 32;
  const int tx = threadIdx.x;
  const int ty = threadIdx.y;
  const bool gate = (n20 >= 1024);
  const int n = (n20 & 1023) + tx;
#pragma unroll
  for (int r = 0; r < 4; ++r) {
    int k = k0 + ty + r * 8;
    float v;
    if (k < D1) v = (gate ? Wg1 : Wo1)[(size_t)k * NOUT + n];
    else        v = (gate ? Wg2 : Wo2)[(size_t)(k - D1) * NOUT + n];
    tile[ty + r * 8][tx] = v;
  }
  __syncthreads();
#pragma unroll
  for (int r = 0; r < 4; ++r) {
    int n2 = n20 + ty + r * 8;
    Wt[(size_t)n2 * KTOT + k0 + tx] = f2bf(tile[tx][ty + r * 8]);
  }
}

// ---------------------------------------------------------------------------
// Kernel 1: fused LN+leaky for BOTH streams, wave-per-row, grid-stride.
// No block barriers; butterfly shuffle reduce across the 64-lane wave.
// ---------------------------------------------------------------------------
__global__ __launch_bounds__(256)
void ln_leaky_all(const float* __restrict__ x1, const float* __restrict__ sc1,
                  const float* __restrict__ bi1,
                  const float* __restrict__ x2, const float* __restrict__ sc2,
                  const float* __restrict__ bi2,
                  unsigned short* __restrict__ f) {
  const int lane = threadIdx.x & 63;
  const int gw = (int)((blockIdx.x * blockDim.x + threadIdx.x) >> 6);
  const int nw = (int)((gridDim.x * blockDim.x) >> 6);

  // ---- stream 1: D=1024, 16 floats/lane (4 x float4)
  for (int r = gw; r < B_ROWS; r += nw) {
    const float4* xr = (const float4*)(x1 + (size_t)r * D1);
    float4 v[4];
    float s = 0.f, ss = 0.f;
#pragma unroll
    for (int k = 0; k < 4; ++k) {
      v[k] = xr[lane + k * 64];
      s += v[k].x + v[k].y + v[k].z + v[k].w;
      ss += v[k].x * v[k].x + v[k].y * v[k].y + v[k].z * v[k].z + v[k].w * v[k].w;
    }
#pragma unroll
    for (int o = 32; o > 0; o >>= 1) { s += __shfl_xor(s, o); ss += __shfl_xor(ss, o); }
    const float mean = s * (1.f / D1);
    const float rstd = rsqrtf(ss * (1.f / D1) - mean * mean + LN_EPS);
    ushort4* dst = (ushort4*)(f + (size_t)r * KTOT);
#pragma unroll
    for (int k = 0; k < 4; ++k) {
      const int idx = lane + k * 64;
      float4 s4 = ((const float4*)sc1)[idx];
      float4 b4 = ((const float4*)bi1)[idx];
      float y0 = (v[k].x - mean) * rstd * s4.x + b4.x; y0 = y0 > 0.f ? y0 : NEG_SLOPE * y0;
      float y1 = (v[k].y - mean) * rstd * s4.y + b4.y; y1 = y1 > 0.f ? y1 : NEG_SLOPE * y1;
      float y2 = (v[k].z - mean) * rstd * s4.z + b4.z; y2 = y2 > 0.f ? y2 : NEG_SLOPE * y2;
      float y3 = (v[k].w - mean) * rstd * s4.w + b4.w; y3 = y3 > 0.f ? y3 : NEG_SLOPE * y3;
      ushort4 pk; pk.x = f2bf(y0); pk.y = f2bf(y1); pk.z = f2bf(y2); pk.w = f2bf(y3);
      dst[idx] = pk;
    }
  }

  // ---- stream 2: D=512, 8 floats/lane (2 x float4)
  for (int r = gw; r < B_ROWS; r += nw) {
    const float4* xr = (const float4*)(x2 + (size_t)r * D2);
    float4 v[2];
    float s = 0.f, ss = 0.f;
#pragma unroll
    for (int k = 0; k < 2; ++k) {
      v[k] = xr[lane + k * 64];
      s += v[k].x + v[k].y + v[k].z + v[k].w;
      ss += v[k].x * v[k].x + v[k].y * v[k].y + v[k].z * v[k].z + v[k].w * v[k].w;
    }
#pragma unroll
    for (int o = 32; o > 0; o >>= 1) { s += __shfl_xor(s, o); ss += __shfl_xor(ss, o); }
    const float mean = s * (1.f / D2);
    const float rstd = rsqrtf(ss * (1.f / D2) - mean * mean + LN_EPS);
    ushort4* dst = (ushort4*)(f + (size_t)r * KTOT + D1);
#pragma unroll
    for (int k = 0; k < 2; ++k) {
      const int idx = lane + k * 64;
      float4 s4 = ((const float4*)sc2)[idx];
      float4 b4 = ((const float4*)bi2)[idx];
      float y0 = (v[k].x - mean) * rstd * s4.x + b4.x; y0 = y0 > 0.f ? y0 : NEG_SLOPE * y0;
      float y1 = (v[k].y - mean) * rstd * s4.y + b4.y; y1 = y1 > 0.f ? y1 : NEG_SLOPE * y1;
      float y2 = (v[k].z - mean) * rstd * s4.z + b4.z; y2 = y2 > 0.f ? y2 : NEG_SLOPE * y2;
      float y3 = (v[k].w - mean) * rstd * s4.w + b4.w; y3 = y3 > 0.f ? y3 : NEG_SLOPE * y3;
      ushort4 pk; pk.x = f2bf(y0); pk.y = f2bf(y1); pk.z = f2bf(y2); pk.w = f2bf(y3);
      dst[idx] = pk;
    }
  }
}

// ---------------------------------------------------------------------------
// Staging: one K-tile (A 256x32, Bo 128x32, Bg 128x32) = 32KB, 4 gloads/thread.
// LDS is linear-written by global_load_lds; swizzle is applied by permuting
// the GLOBAL source: 16B chunk c holds (row = 2p+q, kelem = 8K) where
// p = c>>3, sig = (c&7)^(p&7), q = sig>>2, K = sig&3.  (involution)
// ---------------------------------------------------------------------------
__device__ __forceinline__ void stage_tiles(const unsigned short* __restrict__ F,
                                            const unsigned short* __restrict__ Wt,
                                            int m0, int n0, int k0, int t,
                                            char* buf) {
#pragma unroll
  for (int is = 0; is < 2; ++is) {
    const int c = is * 512 + t;
    const int p = c >> 3;
    const int sig = (c & 7) ^ (p & 7);
    const int row = 2 * p + (sig >> 2);
    const int ke = (sig & 3) * 8;
    gload_lds16(F + (size_t)(m0 + row) * KTOT + k0 + ke, buf + c * 16);
  }
  {
    const int c = t;
    const int p = c >> 3;
    const int sig = (c & 7) ^ (p & 7);
    const int row = 2 * p + (sig >> 2);
    const int ke = (sig & 3) * 8;
    gload_lds16(Wt + (size_t)(n0 + row) * KTOT + k0 + ke, buf + OFF_BO + c * 16);
    gload_lds16(Wt + (size_t)(1024 + n0 + row) * KTOT + k0 + ke, buf + OFF_BG + c * 16);
  }
}

// ---------------------------------------------------------------------------
// Kernel 2: dual-accumulator bf16 MFMA GEMM + gated epilogue.
// 8 waves = 4(M) x 2(N); per-wave 64x64 dual output; 32 MFMA / K-step / wave.
// Triple-buffered, 2-deep prefetch, raw barriers + counted vmcnt(8).
// ---------------------------------------------------------------------------
__global__ __launch_bounds__(THREADS)
void fused_dual_gemm(const unsigned short* __restrict__ F,   // [32768][1536]
                     const unsigned short* __restrict__ Wt,  // [2048][1536]
                     const float* __restrict__ bo1, const float* __restrict__ bo2,
                     const float* __restrict__ bg1, const float* __restrict__ bg2,
                     float* __restrict__ Out) {
  __shared__ __align__(16) char lds[3 * BUF_BYTES];  // 96 KiB

  // XCD-aware bijective swizzle (NBLK=1024, %8==0): each XCD gets a
  // contiguous tm-stripe so the 8 tn-blocks sharing an A-panel co-reside.
  const int bid = blockIdx.x;
  const int swz = (bid & 7) * (NBLK / 8) + (bid >> 3);
  const int m0 = (swz / NT_N) * BM;
  const int n0 = (swz % NT_N) * BN;

  const int t = threadIdx.x;
  const int lane = t & 63;
  const int wave = t >> 6;
  const int wr = wave >> 1;  // 0..3, 64-row stripe
  const int wc = wave & 1;   // 0..1, 64-col stripe

  // fragment LDS byte offsets (loop-invariant): read side of the involution
  const int kq = lane >> 4;  // which 8-elem k-slice (0..3)
  int aoff[4], boff[4];
#pragma unroll
  for (int i = 0; i < 4; ++i) {
    const int ar = wr * 64 + i * 16 + (lane & 15);
    const int pa = ar >> 1;
    const int sa = (((ar & 1) << 2) | kq) ^ (pa & 7);
    aoff[i] = pa * 128 + sa * 16;
    const int br = wc * 64 + i * 16 + (lane & 15);
    const int pb = br >> 1;
    const int sb = (((br & 1) << 2) | kq) ^ (pb & 7);
    boff[i] = pb * 128 + sb * 16;
  }

  f32x4 acc_o[4][4], acc_g[4][4];
#pragma unroll
  for (int i = 0; i < 4; ++i)
#pragma unroll
    for (int j = 0; j < 4; ++j) { acc_o[i][j] = (f32x4)0.f; acc_g[i][j] = (f32x4)0.f; }

  // prologue: prefetch tiles 0 and 1
  stage_tiles(F, Wt, m0, n0, 0, t, lds);
  stage_tiles(F, Wt, m0, n0, BK, t, lds + BUF_BYTES);

  for (int kt = 0; kt < KSTEPS; ++kt) {
    if (kt + 2 < KSTEPS)
      stage_tiles(F, Wt, m0, n0, (kt + 2) * BK, t, lds + ((kt + 2) % 3) * BUF_BYTES);
    // wait: this step's tile resident; up to 2 newer stages (8 loads) in flight
    if (kt < KSTEPS - 2)       asm volatile("s_waitcnt vmcnt(8)" ::: "memory");
    else if (kt == KSTEPS - 2) asm volatile("s_waitcnt vmcnt(4)" ::: "memory");
    else                       asm volatile("s_waitcnt vmcnt(0)" ::: "memory");
    __builtin_amdgcn_s_barrier();

    const char* buf = lds + (kt % 3) * BUF_BYTES;
    bf16x8 af[4], bof[4], bgf[4];
#pragma unroll
    for (int i = 0; i < 4; ++i) {
      af[i]  = *(const bf16x8*)(buf + aoff[i]);
      bof[i] = *(const bf16x8*)(buf + OFF_BO + boff[i]);
      bgf[i] = *(const bf16x8*)(buf + OFF_BG + boff[i]);
    }
#pragma unroll
    for (int i = 0; i < 4; ++i)
#pragma unroll
      for (int j = 0; j < 4; ++j) {
        acc_o[i][j] = __builtin_amdgcn_mfma_f32_16x16x32_bf16(af[i], bof[j], acc_o[i][j], 0, 0, 0);
        acc_g[i][j] = __builtin_amdgcn_mfma_f32_16x16x32_bf16(af[i], bgf[j], acc_g[i][j], 0, 0, 0);
      }
    // this wave's ds_reads must be COMPLETE before others' next stage lands
    asm volatile("s_waitcnt lgkmcnt(0)" ::: "memory");
    __builtin_amdgcn_s_barrier();
  }

  // epilogue: D[row=(lane>>4)*4+r][col=lane&15] per 16x16 frag
#pragma unroll
  for (int j = 0; j < 4; ++j) {
    const int n = n0 + wc * 64 + j * 16 + (lane & 15);
    const float bo = bo1[n] + bo2[n];
    const float bg = bg1[n] + bg2[n];
#pragma unroll
    for (int i = 0; i < 4; ++i) {
      const int mbase = m0 + wr * 64 + i * 16 + (lane >> 4) * 4;
#pragma unroll
      for (int r = 0; r < 4; ++r) {
        const float o = acc_o[i][j][r] + bo;
        const float g = acc_g[i][j][r] + bg;
        const float sgm = 1.f / (1.f + __expf(-g));
        Out[(size_t)(mbase + r) * NOUT + n] = sgm * o;
      }
    }
  }
}

// ---------------------------------------------------------------------------
extern "C" void kernel_launch(void* const* d_in, const int* in_sizes, int n_in,
                              void* d_out, int out_size, void* d_ws, size_t ws_size,
                              hipStream_t stream) {
  const float* x1 = (const float*)d_in[0];
  const float* x2 = (const float*)d_in[1];
  const float* ln_s1 = (const float*)d_in[2];
  const float* ln_b1 = (const float*)d_in[3];
  const float* ln_s2 = (const float*)d_in[4];
  const float* ln_b2 = (const float*)d_in[5];
  const float* Wo1 = (const float*)d_in[6];
  const float* bo1 = (const float*)d_in[7];
  const float* Wo2 = (const float*)d_in[8];
  const float* bo2 = (const float*)d_in[9];
  const float* Wg1 = (const float*)d_in[10];
  const float* bg1 = (const float*)d_in[11];
  const float* Wg2 = (const float*)d_in[12];
  const float* bg2 = (const float*)d_in[13];
  float* out = (float*)d_out;

  unsigned short* f = (unsigned short*)d_ws;                 // [32768][1536] bf16
  const size_t F_BYTES = (size_t)B_ROWS * KTOT * 2;          // 96 MiB
  unsigned short* Wt = (unsigned short*)((char*)d_ws + F_BYTES);  // [2048][1536]

  prep_wt<<<dim3(KTOT / 32, 2048 / 32), dim3(32, 8), 0, stream>>>(Wo1, Wo2, Wg1, Wg2, Wt);
  ln_leaky_all<<<2048, 256, 0, stream>>>(x1, ln_s1, ln_b1, x2, ln_s2, ln_b2, f);
  fused_dual_gemm<<<NBLK, THREADS, 0, stream>>>(f, Wt, bo1, bo2, bg1, bg2, out);
}